// Round 1
// baseline (358.532 us; speedup 1.0000x reference)
//
#include <hip/hip_runtime.h>
#include <math.h>

#define D 128
#define NE 8192
#define NT 8192
#define KEXT 384   // [Ah|Ah|Al] x [Bh|Bl|Bh] -> Ah.Bh + Ah.Bl + Al.Bh
#define SB 16      // samples per projection block

typedef __bf16 bf16x8 __attribute__((ext_vector_type(8)));
typedef float f32x4 __attribute__((ext_vector_type(4)));

__device__ __forceinline__ unsigned short f32_to_bf16(float f) {
  unsigned int u = __float_as_uint(f);
  u += 0x7FFFu + ((u >> 16) & 1u);   // RNE
  return (unsigned short)(u >> 16);
}
__device__ __forceinline__ float bf16_to_f32(unsigned short h) {
  return __uint_as_float(((unsigned int)h) << 16);
}

#define GLOAD_LDS16(g, l)                                                      \
  __builtin_amdgcn_global_load_lds(                                            \
      (__attribute__((address_space(1))) const void*)(g),                      \
      (__attribute__((address_space(3))) void*)(l), 16, 0, 0)

// ---------------------------------------------------------------- prep: M = W @ U_k
__global__ __launch_bounds__(128) void prep_M(const float* __restrict__ W,
                                              const float* __restrict__ U,
                                              float* __restrict__ M) {
  const int d = blockIdx.x;
  const int k = threadIdx.x;
  const float* Wr = W + d * D;
  float acc = 0.f;
#pragma unroll 8
  for (int c = 0; c < D; ++c) acc += Wr[c] * U[c * D + k];
  M[d * D + k] = acc;  // M[d][k] = (W@U_k)[d][k]; y[k] = sum_d M[d][k] v[d]
}

// ---------------------------------------------------------------- projection + scores + bf16 hi/lo split
__global__ __launch_bounds__(128) void project_kernel(
    const float* __restrict__ Xe, const float* __restrict__ Xt,
    const float* __restrict__ miu, const float* __restrict__ M,
    const float* __restrict__ Qh, const float* __restrict__ lam,
    unsigned short* __restrict__ Aext, unsigned short* __restrict__ Bext,
    float* __restrict__ s1, float* __restrict__ s2) {
  const int t = threadIdx.x;          // t = dim d (phase 1) / output k (matvecs)
  const int mode = blockIdx.y;        // 0 = enroll, 1 = test
  const int n0 = blockIdx.x * SB;
  const float* X = mode ? Xt : Xe;
  unsigned short* Ext = mode ? Bext : Aext;
  float* sc = mode ? s2 : s1;

  __shared__ __align__(16) float V[D][20];  // [d][s], pad 20 (16B-aligned rows)
  __shared__ __align__(16) float Y[D][20];
  __shared__ float rn[SB];

  // phase 1: load + center, V[d][s] = x - miu
  const float mu = miu[t];
#pragma unroll
  for (int i = 0; i < SB; ++i)
    V[t][i] = X[(size_t)(n0 + i) * D + t] - mu;
  __syncthreads();

  // per-sample inverse norm
  if (t < SB) {
    float s = 0.f;
#pragma unroll 8
    for (int d = 0; d < D; ++d) { float v = V[d][t]; s += v * v; }
    rn[t] = 1.0f / (sqrtf(s) + 1e-8f);
  }
  __syncthreads();

  // matvec1: y[k][s] = sum_d M[d][k] * V[d][s]   (norm folded in afterwards)
  float y[SB];
#pragma unroll
  for (int s = 0; s < SB; ++s) y[s] = 0.f;
  {
    const float* Mc = M + t;
#pragma unroll 4
    for (int d = 0; d < D; ++d) {
      float m = Mc[d * D];
#pragma unroll
      for (int s4 = 0; s4 < SB / 4; ++s4) {
        float4 v = *(const float4*)&V[d][s4 * 4];
        y[s4 * 4 + 0] += m * v.x;
        y[s4 * 4 + 1] += m * v.y;
        y[s4 * 4 + 2] += m * v.z;
        y[s4 * 4 + 3] += m * v.w;
      }
    }
  }
#pragma unroll
  for (int s = 0; s < SB; ++s) y[s] *= rn[s];

  // stage Y for matvec2 broadcasts
#pragma unroll
  for (int s4 = 0; s4 < SB / 4; ++s4) {
    float4 v;
    v.x = y[s4 * 4 + 0]; v.y = y[s4 * 4 + 1];
    v.z = y[s4 * 4 + 2]; v.w = y[s4 * 4 + 3];
    *(float4*)&Y[t][s4 * 4] = v;
  }
  __syncthreads();

  // matvec2: z[k][s] = sum_d Qh[d][k] * Y[d][s]   (Q_hat symmetric)
  float z[SB];
#pragma unroll
  for (int s = 0; s < SB; ++s) z[s] = 0.f;
  {
    const float* Qc = Qh + t;
#pragma unroll 4
    for (int d = 0; d < D; ++d) {
      float q = Qc[d * D];
#pragma unroll
      for (int s4 = 0; s4 < SB / 4; ++s4) {
        float4 v = *(const float4*)&Y[d][s4 * 4];
        z[s4 * 4 + 0] += q * v.x;
        z[s4 * 4 + 1] += q * v.y;
        z[s4 * 4 + 2] += q * v.z;
        z[s4 * 4 + 3] += q * v.w;
      }
    }
  }

  // score[s] = sum_k y*z : block tree-reduction (reuse V; matvec1 done => safe)
#pragma unroll
  for (int s = 0; s < SB; ++s) V[t][s] = y[s] * z[s];
  __syncthreads();
  for (int st = 64; st >= 1; st >>= 1) {
    if (t < st) {
#pragma unroll
      for (int s = 0; s < SB; ++s) V[t][s] += V[t + st][s];
    }
    __syncthreads();
  }
  if (t < SB) sc[n0 + t] = V[0][t];

  // bf16 hi/lo split rows: enroll [h,h,l] (x 2*lam), test [h,l,h]
  const float scale = mode ? 1.0f : 2.0f * lam[t];
#pragma unroll
  for (int s = 0; s < SB; ++s) {
    float w = y[s] * scale;
    unsigned short hi = f32_to_bf16(w);
    unsigned short lo = f32_to_bf16(w - bf16_to_f32(hi));
    size_t base = (size_t)(n0 + s) * KEXT;
    Ext[base + t]         = hi;
    Ext[base + D + t]     = mode ? lo : hi;
    Ext[base + 2 * D + t] = mode ? hi : lo;
  }
}

// ---------------------------------------------------------------- main GEMM (m97 structure)
// C[n][m] = sum_kext A[n][kext]*B[m][kext] + s1[n] + s2[m]
__global__ __launch_bounds__(256) void gemm_score(
    const unsigned short* __restrict__ A,  // [NE][KEXT] bf16 bits
    const unsigned short* __restrict__ B,  // [NT][KEXT] bf16 bits
    const float* __restrict__ s1, const float* __restrict__ s2,
    float* __restrict__ C) {
  __shared__ __align__(16) unsigned short As[128 * 32];
  __shared__ __align__(16) unsigned short Bs[128 * 32];

  const int t = threadIdx.x;
  const int l = t & 63;
  const int w = t >> 6;     // wave 0..3
  const int wr = w >> 1;    // wave row 0..1
  const int wc = w & 1;     // wave col 0..1
  const int bm0 = blockIdx.y * 128;
  const int bn0 = blockIdx.x * 128;

  f32x4 acc[4][4];
  const f32x4 zero = {0.f, 0.f, 0.f, 0.f};
#pragma unroll
  for (int m = 0; m < 4; ++m)
#pragma unroll
    for (int n = 0; n < 4; ++n) acc[m][n] = zero;

  const int srow = t >> 2;        // 0..63: row within 64-row slab
  const int scol = (t & 3) * 8;   // 8-elem (16B) chunk within 32-k tile
  const int rr = l & 15;
  const int kgo = (l >> 4) * 8;

  for (int kt = 0; kt < KEXT / 32; ++kt) {
    // stage A,B tiles: 2x global_load_lds dwordx4 each (4KB per instr)
#pragma unroll
    for (int j = 0; j < 2; ++j) {
      const unsigned short* ga =
          A + (size_t)(bm0 + j * 64 + srow) * KEXT + kt * 32 + scol;
      GLOAD_LDS16(ga, As + j * 2048 + t * 8);
      const unsigned short* gb =
          B + (size_t)(bn0 + j * 64 + srow) * KEXT + kt * 32 + scol;
      GLOAD_LDS16(gb, Bs + j * 2048 + t * 8);
    }
    __syncthreads();  // compiler drains vmcnt before barrier

    bf16x8 af[4], bf[4];
#pragma unroll
    for (int m = 0; m < 4; ++m)
      af[m] = *(const bf16x8*)(As + (wr * 64 + m * 16 + rr) * 32 + kgo);
#pragma unroll
    for (int n = 0; n < 4; ++n)
      bf[n] = *(const bf16x8*)(Bs + (wc * 64 + n * 16 + rr) * 32 + kgo);

#pragma unroll
    for (int m = 0; m < 4; ++m)
#pragma unroll
      for (int n = 0; n < 4; ++n)
        acc[m][n] =
            __builtin_amdgcn_mfma_f32_16x16x32_bf16(af[m], bf[n], acc[m][n], 0, 0, 0);
    __syncthreads();
  }

  // epilogue: + s1[n] + s2[m]
  const int rq = l >> 4;
  float s2v[4];
#pragma unroll
  for (int n = 0; n < 4; ++n) s2v[n] = s2[bn0 + wc * 64 + n * 16 + rr];
#pragma unroll
  for (int m = 0; m < 4; ++m) {
#pragma unroll
    for (int r = 0; r < 4; ++r) {
      const int row = bm0 + wr * 64 + m * 16 + rq * 4 + r;
      const float s1v = s1[row];
      float* cp = C + (size_t)row * NT + bn0 + wc * 64 + rr;
#pragma unroll
      for (int n = 0; n < 4; ++n) cp[n * 16] = acc[m][n][r] + s1v + s2v[n];
    }
  }
}

// ----------------------------------------------------------------
extern "C" void kernel_launch(void* const* d_in, const int* in_sizes, int n_in,
                              void* d_out, int out_size, void* d_ws, size_t ws_size,
                              hipStream_t stream) {
  const float* x_enroll = (const float*)d_in[0];
  const float* x_test   = (const float*)d_in[1];
  const float* W        = (const float*)d_in[2];
  const float* miu      = (const float*)d_in[3];
  const float* lam      = (const float*)d_in[4];
  const float* U_k      = (const float*)d_in[5];
  const float* Q_hat    = (const float*)d_in[6];
  float* out = (float*)d_out;

  char* ws = (char*)d_ws;
  float* M  = (float*)ws;                       // 64 KB
  float* s1 = (float*)(ws + 65536);             // 32 KB
  float* s2 = (float*)(ws + 98304);             // 32 KB
  unsigned short* Aext = (unsigned short*)(ws + 131072);             // 6 MB
  unsigned short* Bext = (unsigned short*)(ws + 131072 + 6291456);   // 6 MB

  prep_M<<<dim3(D), dim3(D), 0, stream>>>(W, U_k, M);
  project_kernel<<<dim3(NE / SB, 2), dim3(128), 0, stream>>>(
      x_enroll, x_test, miu, M, Q_hat, lam, Aext, Bext, s1, s2);
  gemm_score<<<dim3(NT / 128, NE / 128), dim3(256), 0, stream>>>(
      Aext, Bext, s1, s2, out);
}